// Round 1
// baseline (106.279 us; speedup 1.0000x reference)
//
#include <hip/hip_runtime.h>

#define B_ 8
#define T_ 2048
#define C_ 1024
#define H_ 64
#define BT_ (B_ * T_)

typedef float f32x4 __attribute__((ext_vector_type(4)));
typedef unsigned short u16x4 __attribute__((ext_vector_type(4)));
typedef unsigned short u16x8 __attribute__((ext_vector_type(8)));
typedef __bf16 bf16x8 __attribute__((ext_vector_type(8)));

// f32 -> bf16 round-to-nearest-even
static __device__ __forceinline__ unsigned short f2bf(float f) {
    unsigned int u = __builtin_bit_cast(unsigned int, f);
    u = (u + 0x7FFFu + ((u >> 16) & 1u)) >> 16;
    return (unsigned short)u;
}

static __device__ __forceinline__ f32x4 mfma16(u16x8 a, u16x8 b, f32x4 c) {
    return __builtin_amdgcn_mfma_f32_16x16x32_bf16(
        __builtin_bit_cast(bf16x8, a), __builtin_bit_cast(bf16x8, b), c, 0, 0, 0);
}

// ---------------------------------------------------------------------------
// Kernel 1: W [1024][64] f32 (x3) -> Wt [192][1024] bf16 (row n = output chan,
// k-contiguous) so GEMM B-fragments read 16B contiguous.
// grid: 48 blocks (3 arrays x 16 c-tiles), 256 threads
// ---------------------------------------------------------------------------
__global__ __launch_bounds__(256) void wprep(const float* __restrict__ Wk,
                                             const float* __restrict__ Wq,
                                             const float* __restrict__ Wv,
                                             unsigned short* __restrict__ wt) {
    __shared__ float tile[64][65];
    const int arr = blockIdx.x >> 4, ct = blockIdx.x & 15;
    const float* W = (arr == 0) ? Wk : ((arr == 1) ? Wq : Wv);
    const int tid = threadIdx.x;
    {
        int c = tid >> 2, seg = (tid & 3) << 4;
        const float* src = W + (size_t)(ct * 64 + c) * 64 + seg;
#pragma unroll
        for (int j = 0; j < 16; j += 4) {
            f32x4 v4 = *(const f32x4*)(src + j);
            tile[c][seg + j + 0] = v4[0];
            tile[c][seg + j + 1] = v4[1];
            tile[c][seg + j + 2] = v4[2];
            tile[c][seg + j + 3] = v4[3];
        }
    }
    __syncthreads();
    {
        int h = tid >> 2, cs = (tid & 3) << 4;
        unsigned short* dst = wt + (size_t)(arr * 64 + h) * 1024 + ct * 64 + cs;
#pragma unroll
        for (int j = 0; j < 16; ++j) dst[j] = f2bf(tile[cs + j][h]);
    }
}

// ---------------------------------------------------------------------------
// Kernel 2: kqv projection GEMM. C[16384][192] = idx[16384][1024] x Wt^T.
// BM=64, BK=64, 4 waves; each wave: 4 m-frags x 3 n-frags (48 cols).
// Outputs: kw/qw row-major bf16 [BT][64]; v transposed -> vtw [64][BT].
// LDS 16B-unit XOR swizzle (unit ^ (row&7)) keeps ds_read_b128 conflict-free.
// grid: 256 blocks, 256 threads
// ---------------------------------------------------------------------------
__global__ __launch_bounds__(256) void proj_gemm(const float* __restrict__ idx,
                                                 const unsigned short* __restrict__ wt,
                                                 unsigned short* __restrict__ kw,
                                                 unsigned short* __restrict__ qw,
                                                 unsigned short* __restrict__ vtw) {
    __shared__ unsigned short As[2][64 * 64];    // 16 KB
    __shared__ unsigned short Bs[2][192 * 64];   // 48 KB
    const int tid = threadIdx.x;
    const int lane = tid & 63, w = tid >> 6;
    const int g = lane >> 4, l15 = lane & 15;
    const int m0 = blockIdx.x * 64;
    const int arow = tid >> 2, aseg = tid & 3;

    f32x4 acc[4][3] = {};
    f32x4 areg[4];
    u16x8 breg[6];

    // ---- prologue: stage kt=0 into buffer 0 ----
    {
        const float* src = idx + (size_t)(m0 + arow) * 1024 + aseg * 16;
        areg[0] = ((const f32x4*)src)[0];
        areg[1] = ((const f32x4*)src)[1];
        areg[2] = ((const f32x4*)src)[2];
        areg[3] = ((const f32x4*)src)[3];
#pragma unroll
        for (int i = 0; i < 6; ++i) {
            int slot = i * 256 + tid, n = slot >> 3, u = slot & 7;
            breg[i] = *(const u16x8*)(wt + (size_t)n * 1024 + u * 8);
        }
        u16x8 c0, c1;
#pragma unroll
        for (int e = 0; e < 4; ++e) {
            c0[e] = f2bf(areg[0][e]); c0[e + 4] = f2bf(areg[1][e]);
            c1[e] = f2bf(areg[2][e]); c1[e + 4] = f2bf(areg[3][e]);
        }
        *(u16x8*)&As[0][arow * 64 + (((aseg * 2) ^ (arow & 7)) * 8)] = c0;
        *(u16x8*)&As[0][arow * 64 + (((aseg * 2 + 1) ^ (arow & 7)) * 8)] = c1;
#pragma unroll
        for (int i = 0; i < 6; ++i) {
            int slot = i * 256 + tid, n = slot >> 3, u = slot & 7;
            *(u16x8*)&Bs[0][n * 64 + ((u ^ (n & 7)) * 8)] = breg[i];
        }
    }
    __syncthreads();

    int cur = 0;
    for (int kt = 0; kt < 16; ++kt) {
        // issue next-tile loads early (latency hides under MFMA)
        if (kt < 15) {
            int k0n = (kt + 1) * 64;
            const float* src = idx + (size_t)(m0 + arow) * 1024 + k0n + aseg * 16;
            areg[0] = ((const f32x4*)src)[0];
            areg[1] = ((const f32x4*)src)[1];
            areg[2] = ((const f32x4*)src)[2];
            areg[3] = ((const f32x4*)src)[3];
#pragma unroll
            for (int i = 0; i < 6; ++i) {
                int slot = i * 256 + tid, n = slot >> 3, u = slot & 7;
                breg[i] = *(const u16x8*)(wt + (size_t)n * 1024 + k0n + u * 8);
            }
        }
        // compute on current buffer
#pragma unroll
        for (int ks = 0; ks < 2; ++ks) {
            u16x8 a[4], b[3];
#pragma unroll
            for (int mf = 0; mf < 4; ++mf)
                a[mf] = *(const u16x8*)&As[cur][(mf * 16 + l15) * 64 +
                                                (((ks * 4 + g) ^ (l15 & 7)) * 8)];
#pragma unroll
            for (int nf = 0; nf < 3; ++nf) {
                int n = w * 48 + nf * 16 + l15;
                b[nf] = *(const u16x8*)&Bs[cur][n * 64 + (((ks * 4 + g) ^ (n & 7)) * 8)];
            }
#pragma unroll
            for (int mf = 0; mf < 4; ++mf)
#pragma unroll
                for (int nf = 0; nf < 3; ++nf)
                    acc[mf][nf] = mfma16(a[mf], b[nf], acc[mf][nf]);
        }
        // write next tile into the other buffer
        if (kt < 15) {
            u16x8 c0, c1;
#pragma unroll
            for (int e = 0; e < 4; ++e) {
                c0[e] = f2bf(areg[0][e]); c0[e + 4] = f2bf(areg[1][e]);
                c1[e] = f2bf(areg[2][e]); c1[e + 4] = f2bf(areg[3][e]);
            }
            *(u16x8*)&As[cur ^ 1][arow * 64 + (((aseg * 2) ^ (arow & 7)) * 8)] = c0;
            *(u16x8*)&As[cur ^ 1][arow * 64 + (((aseg * 2 + 1) ^ (arow & 7)) * 8)] = c1;
#pragma unroll
            for (int i = 0; i < 6; ++i) {
                int slot = i * 256 + tid, n = slot >> 3, u = slot & 7;
                *(u16x8*)&Bs[cur ^ 1][n * 64 + ((u ^ (n & 7)) * 8)] = breg[i];
            }
        }
        __syncthreads();
        cur ^= 1;
    }

    // ---- epilogue: D layout col=lane&15, row=g*4+reg ----
#pragma unroll
    for (int nf = 0; nf < 3; ++nf) {
        int nb = 3 * w + nf;             // 16-col block 0..11
        int arr = nb >> 2;               // 0=k 1=q 2=v
        int nloc = ((nb & 3) << 4) + l15;
#pragma unroll
        for (int mf = 0; mf < 4; ++mf) {
            f32x4 ac = acc[mf][nf];
            int row = m0 + mf * 16 + g * 4;
            if (arr == 2) {
                u16x4 pk = {f2bf(ac[0]), f2bf(ac[1]), f2bf(ac[2]), f2bf(ac[3])};
                *(u16x4*)&vtw[(size_t)nloc * BT_ + row] = pk;   // vT[h][row]
            } else {
                unsigned short* dst = arr ? qw : kw;
                dst[(size_t)(row + 0) * 64 + nloc] = f2bf(ac[0]);
                dst[(size_t)(row + 1) * 64 + nloc] = f2bf(ac[1]);
                dst[(size_t)(row + 2) * 64 + nloc] = f2bf(ac[2]);
                dst[(size_t)(row + 3) * 64 + nloc] = f2bf(ac[3]);
            }
        }
    }
}

// ---------------------------------------------------------------------------
// Kernel 3: causal attention, flash-style. wei = k·q^T/8 (k is the "query").
// 1 wave/block, 32 t-rows/wave (2 t-frags), s-tiles of 64.
// S^T = mfma(A=q rows, B=k rows): D col = t (lane&15) -> softmax state is
// per-lane scalar; O^T = mfma(A=vT, B=P) keeps col=t -> scalar rescale,
// float4 output stores. P transposed through 2KB wave-private LDS.
// grid: 512 blocks (b, t-tile reversed: big blocks first), 64 threads
// ---------------------------------------------------------------------------
__global__ __launch_bounds__(64) void attn(const unsigned short* __restrict__ kw,
                                           const unsigned short* __restrict__ qw,
                                           const unsigned short* __restrict__ vtw,
                                           float* __restrict__ out) {
    __shared__ unsigned short q_lds[2][64 * 64];  // 16 KB
    __shared__ unsigned short v_lds[2][64 * 64];  // 16 KB
    __shared__ unsigned short p_lds[32 * 64];     // 4 KB
    const int lane = threadIdx.x;
    const int g = lane >> 4, l15 = lane & 15;
    const int bid = blockIdx.x;
    const int b = bid >> 6;
    const int tile = 63 - (bid & 63);     // reverse: longest blocks launch first
    const int t0 = tile * 32;
    const size_t base = (size_t)b * T_;

    // hoisted K-operand fragments (k rows for this wave's 32 t)
    u16x8 kf[2][2];
#pragma unroll
    for (int tf = 0; tf < 2; ++tf) {
        const unsigned short* kr = kw + (size_t)(base + t0 + tf * 16 + l15) * 64;
        kf[tf][0] = *(const u16x8*)(kr + g * 8);
        kf[tf][1] = *(const u16x8*)(kr + 32 + g * 8);
    }

    f32x4 o[4][2] = {};
    float m_run[2] = {-1e30f, -1e30f};
    float l_run[2] = {0.f, 0.f};
    const int nS = (t0 >> 6) + 1;

    // prologue: stage s-tile 0 into buffer 0 (swizzle-on-write)
#pragma unroll
    for (int i = 0; i < 8; ++i) {
        int r = i * 8 + (lane >> 3), u = lane & 7;
        u16x8 q8 = *(const u16x8*)(qw + (size_t)(base + r) * 64 + u * 8);
        u16x8 v8 = *(const u16x8*)(vtw + (size_t)r * BT_ + base + u * 8);
        *(u16x8*)&q_lds[0][r * 64 + ((u ^ (r & 7)) * 8)] = q8;
        *(u16x8*)&v_lds[0][r * 64 + ((u ^ (r & 7)) * 8)] = v8;
    }

    int cur = 0;
    for (int st = 0; st < nS; ++st) {
        const int s0 = st << 6;
        const int s0n = (st + 1 < nS) ? s0 + 64 : s0;   // dummy restage on last
        // prefetch next tile into registers (consumed after compute)
        u16x8 qreg[8], vreg[8];
#pragma unroll
        for (int i = 0; i < 8; ++i) {
            int r = i * 8 + (lane >> 3), u = lane & 7;
            qreg[i] = *(const u16x8*)(qw + (size_t)(base + s0n + r) * 64 + u * 8);
            vreg[i] = *(const u16x8*)(vtw + (size_t)r * BT_ + (base + s0n) + u * 8);
        }

        // ---- QK^T (S^T accumulate over h) ----
        f32x4 s_[4][2] = {};
#pragma unroll
        for (int ks = 0; ks < 2; ++ks) {
            u16x8 a[4];
#pragma unroll
            for (int sf = 0; sf < 4; ++sf)
                a[sf] = *(const u16x8*)&q_lds[cur][(sf * 16 + l15) * 64 +
                                                   (((ks * 4 + g) ^ (l15 & 7)) * 8)];
#pragma unroll
            for (int sf = 0; sf < 4; ++sf)
#pragma unroll
                for (int tf = 0; tf < 2; ++tf)
                    s_[sf][tf] = mfma16(a[sf], kf[tf][ks], s_[sf][tf]);
        }

        // ---- online softmax (per t = lane&15 column) ----
        const bool dg = (s0 + 63 > t0);   // only diagonal tile needs masking
#pragma unroll
        for (int tf = 0; tf < 2; ++tf) {
            const int t = t0 + tf * 16 + l15;
            float p[4][4];
            float tm = -1e30f;
#pragma unroll
            for (int sf = 0; sf < 4; ++sf)
#pragma unroll
                for (int r = 0; r < 4; ++r) {
                    int sg = s0 + sf * 16 + g * 4 + r;
                    float x = s_[sf][tf][r] * 0.125f;
                    x = (dg && sg > t) ? -1e30f : x;
                    p[sf][r] = x;
                    tm = fmaxf(tm, x);
                }
            tm = fmaxf(tm, __shfl_xor(tm, 16));
            tm = fmaxf(tm, __shfl_xor(tm, 32));
            float mnew = fmaxf(m_run[tf], tm);
            float cf = exp2f((m_run[tf] - mnew) * 1.44269504f);
            m_run[tf] = mnew;
            float ps = 0.f;
#pragma unroll
            for (int sf = 0; sf < 4; ++sf)
#pragma unroll
                for (int r = 0; r < 4; ++r) {
                    float e = exp2f((p[sf][r] - mnew) * 1.44269504f);
                    p[sf][r] = e;
                    ps += e;
                }
            ps += __shfl_xor(ps, 16);
            ps += __shfl_xor(ps, 32);
            l_run[tf] = l_run[tf] * cf + ps;
#pragma unroll
            for (int mf = 0; mf < 4; ++mf) o[mf][tf] *= cf;
            // pack P -> LDS (row t, ushort index = s, swizzled 16B units)
            const int trow = tf * 16 + l15;
#pragma unroll
            for (int sf = 0; sf < 4; ++sf) {
                u16x4 pk = {f2bf(p[sf][0]), f2bf(p[sf][1]), f2bf(p[sf][2]), f2bf(p[sf][3])};
                int u16i = (sf * 2 + (g >> 1)) ^ (l15 & 7);
                *(u16x4*)&p_lds[trow * 64 + u16i * 8 + (g & 1) * 4] = pk;
            }
        }

        // ---- PV: O^T[h][t] += vT x P ----
#pragma unroll
        for (int ks = 0; ks < 2; ++ks) {
            u16x8 bp[2];
#pragma unroll
            for (int tf = 0; tf < 2; ++tf)
                bp[tf] = *(const u16x8*)&p_lds[(tf * 16 + l15) * 64 +
                                               (((ks * 4 + g) ^ (l15 & 7)) * 8)];
#pragma unroll
            for (int mf = 0; mf < 4; ++mf) {
                u16x8 av = *(const u16x8*)&v_lds[cur][(mf * 16 + l15) * 64 +
                                                      (((ks * 4 + g) ^ (l15 & 7)) * 8)];
#pragma unroll
                for (int tf = 0; tf < 2; ++tf)
                    o[mf][tf] = mfma16(av, bp[tf], o[mf][tf]);
            }
        }

        // ---- commit prefetched tile to the other buffer ----
#pragma unroll
        for (int i = 0; i < 8; ++i) {
            int r = i * 8 + (lane >> 3), u = lane & 7;
            *(u16x8*)&q_lds[cur ^ 1][r * 64 + ((u ^ (r & 7)) * 8)] = qreg[i];
            *(u16x8*)&v_lds[cur ^ 1][r * 64 + ((u ^ (r & 7)) * 8)] = vreg[i];
        }
        cur ^= 1;
    }

    // ---- output: O^T col=t per lane, rows h contiguous -> float4 stores ----
#pragma unroll
    for (int tf = 0; tf < 2; ++tf) {
        float inv = 1.f / l_run[tf];
        int t = t0 + tf * 16 + l15;
        float* orow = out + (size_t)(base + t) * 64;
#pragma unroll
        for (int mf = 0; mf < 4; ++mf) {
            f32x4 r = o[mf][tf] * inv;
            *(f32x4*)(orow + mf * 16 + g * 4) = r;
        }
    }
}

// ---------------------------------------------------------------------------
extern "C" void kernel_launch(void* const* d_in, const int* in_sizes, int n_in,
                              void* d_out, int out_size, void* d_ws, size_t ws_size,
                              hipStream_t stream) {
    const float* idx = (const float*)d_in[0];
    const float* Wk = (const float*)d_in[1];
    const float* Wq = (const float*)d_in[2];
    const float* Wv = (const float*)d_in[3];
    float* out = (float*)d_out;

    // workspace layout (bf16): Wt[192*1024] | k[BT*64] | q[BT*64] | vT[64*BT]
    unsigned short* wt = (unsigned short*)d_ws;
    unsigned short* kw = wt + 192 * 1024;
    unsigned short* qw = kw + (size_t)BT_ * 64;
    unsigned short* vtw = qw + (size_t)BT_ * 64;

    wprep<<<48, 256, 0, stream>>>(Wk, Wq, Wv, wt);
    proj_gemm<<<256, 256, 0, stream>>>(idx, wt, kw, qw, vtw);
    attn<<<512, 64, 0, stream>>>(kw, qw, vtw, out);
}

// Round 2
// 67.823 us; speedup vs baseline: 1.5670x; 1.5670x over previous
//
#include <hip/hip_runtime.h>

#define B_ 8
#define T_ 2048
#define C_ 1024
#define H_ 64
#define BT_ (B_ * T_)

typedef float f32x4 __attribute__((ext_vector_type(4)));
typedef unsigned short u16x4 __attribute__((ext_vector_type(4)));
typedef unsigned short u16x8 __attribute__((ext_vector_type(8)));
typedef __bf16 bf16x8 __attribute__((ext_vector_type(8)));

// f32 -> bf16 round-to-nearest-even
static __device__ __forceinline__ unsigned short f2bf(float f) {
    unsigned int u = __builtin_bit_cast(unsigned int, f);
    u = (u + 0x7FFFu + ((u >> 16) & 1u)) >> 16;
    return (unsigned short)u;
}

static __device__ __forceinline__ f32x4 mfma16(u16x8 a, u16x8 b, f32x4 c) {
    return __builtin_amdgcn_mfma_f32_16x16x32_bf16(
        __builtin_bit_cast(bf16x8, a), __builtin_bit_cast(bf16x8, b), c, 0, 0, 0);
}

// ---------------------------------------------------------------------------
// Kernel 1: W [1024][64] f32 (x3) -> Wt [192][1024] bf16 (row n = output chan,
// k-contiguous) so GEMM B-fragments read 16B contiguous.
// ---------------------------------------------------------------------------
__global__ __launch_bounds__(256) void wprep(const float* __restrict__ Wk,
                                             const float* __restrict__ Wq,
                                             const float* __restrict__ Wv,
                                             unsigned short* __restrict__ wt) {
    __shared__ float tile[64][65];
    const int arr = blockIdx.x >> 4, ct = blockIdx.x & 15;
    const float* W = (arr == 0) ? Wk : ((arr == 1) ? Wq : Wv);
    const int tid = threadIdx.x;
    {
        int c = tid >> 2, seg = (tid & 3) << 4;
        const float* src = W + (size_t)(ct * 64 + c) * 64 + seg;
#pragma unroll
        for (int j = 0; j < 16; j += 4) {
            f32x4 v4 = *(const f32x4*)(src + j);
            tile[c][seg + j + 0] = v4[0];
            tile[c][seg + j + 1] = v4[1];
            tile[c][seg + j + 2] = v4[2];
            tile[c][seg + j + 3] = v4[3];
        }
    }
    __syncthreads();
    {
        int h = tid >> 2, cs = (tid & 3) << 4;
        unsigned short* dst = wt + (size_t)(arr * 64 + h) * 1024 + ct * 64 + cs;
#pragma unroll
        for (int j = 0; j < 16; ++j) dst[j] = f2bf(tile[cs + j][h]);
    }
}

// ---------------------------------------------------------------------------
// Kernel 2: kqv projection GEMM. C[16384][192] = idx[16384][1024] x Wt^T.
// BM=64, BK=64, 4 waves; each wave: 4 m-frags x 3 n-frags (48 cols).
// Outputs: kw/qw row-major bf16 [BT][64]; v transposed -> vtw [64][BT].
// ---------------------------------------------------------------------------
__global__ __launch_bounds__(256) void proj_gemm(const float* __restrict__ idx,
                                                 const unsigned short* __restrict__ wt,
                                                 unsigned short* __restrict__ kw,
                                                 unsigned short* __restrict__ qw,
                                                 unsigned short* __restrict__ vtw) {
    __shared__ unsigned short As[2][64 * 64];    // 16 KB
    __shared__ unsigned short Bs[2][192 * 64];   // 48 KB
    const int tid = threadIdx.x;
    const int lane = tid & 63, w = tid >> 6;
    const int g = lane >> 4, l15 = lane & 15;
    const int m0 = blockIdx.x * 64;
    const int arow = tid >> 2, aseg = tid & 3;

    f32x4 acc[4][3] = {};
    f32x4 areg[4];
    u16x8 breg[6];

    // ---- prologue: stage kt=0 into buffer 0 ----
    {
        const float* src = idx + (size_t)(m0 + arow) * 1024 + aseg * 16;
        areg[0] = ((const f32x4*)src)[0];
        areg[1] = ((const f32x4*)src)[1];
        areg[2] = ((const f32x4*)src)[2];
        areg[3] = ((const f32x4*)src)[3];
#pragma unroll
        for (int i = 0; i < 6; ++i) {
            int slot = i * 256 + tid, n = slot >> 3, u = slot & 7;
            breg[i] = *(const u16x8*)(wt + (size_t)n * 1024 + u * 8);
        }
        u16x8 c0, c1;
#pragma unroll
        for (int e = 0; e < 4; ++e) {
            c0[e] = f2bf(areg[0][e]); c0[e + 4] = f2bf(areg[1][e]);
            c1[e] = f2bf(areg[2][e]); c1[e + 4] = f2bf(areg[3][e]);
        }
        *(u16x8*)&As[0][arow * 64 + (((aseg * 2) ^ (arow & 7)) * 8)] = c0;
        *(u16x8*)&As[0][arow * 64 + (((aseg * 2 + 1) ^ (arow & 7)) * 8)] = c1;
#pragma unroll
        for (int i = 0; i < 6; ++i) {
            int slot = i * 256 + tid, n = slot >> 3, u = slot & 7;
            *(u16x8*)&Bs[0][n * 64 + ((u ^ (n & 7)) * 8)] = breg[i];
        }
    }
    __syncthreads();

    int cur = 0;
    for (int kt = 0; kt < 16; ++kt) {
        if (kt < 15) {
            int k0n = (kt + 1) * 64;
            const float* src = idx + (size_t)(m0 + arow) * 1024 + k0n + aseg * 16;
            areg[0] = ((const f32x4*)src)[0];
            areg[1] = ((const f32x4*)src)[1];
            areg[2] = ((const f32x4*)src)[2];
            areg[3] = ((const f32x4*)src)[3];
#pragma unroll
            for (int i = 0; i < 6; ++i) {
                int slot = i * 256 + tid, n = slot >> 3, u = slot & 7;
                breg[i] = *(const u16x8*)(wt + (size_t)n * 1024 + k0n + u * 8);
            }
        }
#pragma unroll
        for (int ks = 0; ks < 2; ++ks) {
            u16x8 a[4], b[3];
#pragma unroll
            for (int mf = 0; mf < 4; ++mf)
                a[mf] = *(const u16x8*)&As[cur][(mf * 16 + l15) * 64 +
                                                (((ks * 4 + g) ^ (l15 & 7)) * 8)];
#pragma unroll
            for (int nf = 0; nf < 3; ++nf) {
                int n = w * 48 + nf * 16 + l15;
                b[nf] = *(const u16x8*)&Bs[cur][n * 64 + (((ks * 4 + g) ^ (n & 7)) * 8)];
            }
#pragma unroll
            for (int mf = 0; mf < 4; ++mf)
#pragma unroll
                for (int nf = 0; nf < 3; ++nf)
                    acc[mf][nf] = mfma16(a[mf], b[nf], acc[mf][nf]);
        }
        if (kt < 15) {
            u16x8 c0, c1;
#pragma unroll
            for (int e = 0; e < 4; ++e) {
                c0[e] = f2bf(areg[0][e]); c0[e + 4] = f2bf(areg[1][e]);
                c1[e] = f2bf(areg[2][e]); c1[e + 4] = f2bf(areg[3][e]);
            }
            *(u16x8*)&As[cur ^ 1][arow * 64 + (((aseg * 2) ^ (arow & 7)) * 8)] = c0;
            *(u16x8*)&As[cur ^ 1][arow * 64 + (((aseg * 2 + 1) ^ (arow & 7)) * 8)] = c1;
#pragma unroll
            for (int i = 0; i < 6; ++i) {
                int slot = i * 256 + tid, n = slot >> 3, u = slot & 7;
                *(u16x8*)&Bs[cur ^ 1][n * 64 + ((u ^ (n & 7)) * 8)] = breg[i];
            }
        }
        __syncthreads();
        cur ^= 1;
    }

#pragma unroll
    for (int nf = 0; nf < 3; ++nf) {
        int nb = 3 * w + nf;
        int arr = nb >> 2;
        int nloc = ((nb & 3) << 4) + l15;
#pragma unroll
        for (int mf = 0; mf < 4; ++mf) {
            f32x4 ac = acc[mf][nf];
            int row = m0 + mf * 16 + g * 4;
            if (arr == 2) {
                u16x4 pk = {f2bf(ac[0]), f2bf(ac[1]), f2bf(ac[2]), f2bf(ac[3])};
                *(u16x4*)&vtw[(size_t)nloc * BT_ + row] = pk;
            } else {
                unsigned short* dst = arr ? qw : kw;
                dst[(size_t)(row + 0) * 64 + nloc] = f2bf(ac[0]);
                dst[(size_t)(row + 1) * 64 + nloc] = f2bf(ac[1]);
                dst[(size_t)(row + 2) * 64 + nloc] = f2bf(ac[2]);
                dst[(size_t)(row + 3) * 64 + nloc] = f2bf(ac[3]);
            }
        }
    }
}

// ---------------------------------------------------------------------------
// Kernel 3: causal attention, flash-split across 8 waves per block.
// Block = (b, t-tile of 32 rows); wave w handles s-tiles w, w+8, ... (64 wide),
// keeping private (m, l, O^T) partials; cross-wave combine via LDS at the end.
// S^T = mfma(A=q rows, B=k rows) -> col=t per lane -> scalar softmax state.
// O^T = mfma(A=vT, B=P). q/vT fragments read straight from global (L2/L3
// resident, 6.5 MB total); only P-transpose (4 KB/wave) uses LDS in the loop.
// grid: 512 blocks x 512 threads
// ---------------------------------------------------------------------------
__global__ __launch_bounds__(512, 2) void attn(const unsigned short* __restrict__ kw,
                                               const unsigned short* __restrict__ qw,
                                               const unsigned short* __restrict__ vtw,
                                               float* __restrict__ out) {
    // union: [loop] per-wave P transpose 8x4KB  |  [combine] O[8][32][64] f32 + m,l
    __shared__ __align__(16) char smem[8 * 32 * 64 * 4 + 2 * 8 * 32 * 4];  // 67.5 KB
    const int tid = threadIdx.x;
    const int w = tid >> 6, lane = tid & 63;
    const int g = lane >> 4, l15 = lane & 15;
    const int bid = blockIdx.x;
    const int b = bid >> 6;
    const int tile = 63 - (bid & 63);     // longest blocks launch first
    const int t0 = tile * 32;
    const size_t base = (size_t)b * T_;
    unsigned short* p_my = (unsigned short*)smem + w * 2048;

    // hoisted K-operand fragments (k rows for this block's 32 t)
    u16x8 kf[2][2];
#pragma unroll
    for (int tf = 0; tf < 2; ++tf) {
        const unsigned short* kr = kw + (size_t)(base + t0 + tf * 16 + l15) * 64;
        kf[tf][0] = *(const u16x8*)(kr + g * 8);
        kf[tf][1] = *(const u16x8*)(kr + 32 + g * 8);
    }

    f32x4 o[4][2] = {};
    float m_run[2] = {-1e30f, -1e30f};
    float l_run[2] = {0.f, 0.f};
    const int nS = (t0 >> 6) + 1;

    for (int st = w; st < nS; st += 8) {
        const int s0 = st << 6;

        // ---- q fragments from global (A-operand: lane l15 = s-row) ----
        u16x8 a[2][4];
#pragma unroll
        for (int ks = 0; ks < 2; ++ks)
#pragma unroll
            for (int sf = 0; sf < 4; ++sf)
                a[ks][sf] = *(const u16x8*)(qw + (size_t)(base + s0 + sf * 16 + l15) * 64 +
                                            ks * 32 + g * 8);

        // ---- QK^T (S^T accumulate over h) ----
        f32x4 s_[4][2] = {};
#pragma unroll
        for (int ks = 0; ks < 2; ++ks)
#pragma unroll
            for (int sf = 0; sf < 4; ++sf)
#pragma unroll
                for (int tf = 0; tf < 2; ++tf)
                    s_[sf][tf] = mfma16(a[ks][sf], kf[tf][ks], s_[sf][tf]);

        // ---- v fragments issued now; latency hides under softmax ----
        u16x8 vf[2][4];
#pragma unroll
        for (int ks = 0; ks < 2; ++ks)
#pragma unroll
            for (int mf = 0; mf < 4; ++mf)
                vf[ks][mf] = *(const u16x8*)(vtw + (size_t)(mf * 16 + l15) * BT_ +
                                             base + s0 + ks * 32 + g * 8);

        // ---- online softmax (per t = lane&15 column) ----
        const bool dg = (s0 + 63 > t0);
#pragma unroll
        for (int tf = 0; tf < 2; ++tf) {
            const int t = t0 + tf * 16 + l15;
            float p[4][4];
            float tm = -1e30f;
#pragma unroll
            for (int sf = 0; sf < 4; ++sf)
#pragma unroll
                for (int r = 0; r < 4; ++r) {
                    int sg = s0 + sf * 16 + g * 4 + r;
                    float x = s_[sf][tf][r] * 0.125f;
                    x = (dg && sg > t) ? -1e30f : x;
                    p[sf][r] = x;
                    tm = fmaxf(tm, x);
                }
            tm = fmaxf(tm, __shfl_xor(tm, 16));
            tm = fmaxf(tm, __shfl_xor(tm, 32));
            float mnew = fmaxf(m_run[tf], tm);
            float cf = exp2f((m_run[tf] - mnew) * 1.44269504f);
            m_run[tf] = mnew;
            float ps = 0.f;
#pragma unroll
            for (int sf = 0; sf < 4; ++sf)
#pragma unroll
                for (int r = 0; r < 4; ++r) {
                    float e = exp2f((p[sf][r] - mnew) * 1.44269504f);
                    p[sf][r] = e;
                    ps += e;
                }
            ps += __shfl_xor(ps, 16);
            ps += __shfl_xor(ps, 32);
            l_run[tf] = l_run[tf] * cf + ps;
#pragma unroll
            for (int mf = 0; mf < 4; ++mf) o[mf][tf] *= cf;
            const int trow = tf * 16 + l15;
#pragma unroll
            for (int sf = 0; sf < 4; ++sf) {
                u16x4 pk = {f2bf(p[sf][0]), f2bf(p[sf][1]), f2bf(p[sf][2]), f2bf(p[sf][3])};
                int u16i = (sf * 2 + (g >> 1)) ^ (l15 & 7);
                *(u16x4*)&p_my[trow * 64 + u16i * 8 + (g & 1) * 4] = pk;
            }
        }

        // ---- PV: O^T[h][t] += vT x P ----
#pragma unroll
        for (int ks = 0; ks < 2; ++ks) {
            u16x8 bp[2];
#pragma unroll
            for (int tf = 0; tf < 2; ++tf)
                bp[tf] = *(const u16x8*)&p_my[(tf * 16 + l15) * 64 +
                                              (((ks * 4 + g) ^ (l15 & 7)) * 8)];
#pragma unroll
            for (int mf = 0; mf < 4; ++mf)
#pragma unroll
                for (int tf = 0; tf < 2; ++tf)
                    o[mf][tf] = mfma16(vf[ks][mf], bp[tf], o[mf][tf]);
        }
    }

    // ---- cross-wave combine ----
    __syncthreads();   // all waves done with p region before O aliases it
    float* O_lds = (float*)smem;                  // [w][t][64], XOR-swizzled units
    float* m_lds = (float*)(smem + 8 * 32 * 64 * 4);
    float* l_lds = m_lds + 8 * 32;
#pragma unroll
    for (int tf = 0; tf < 2; ++tf) {
        int t = tf * 16 + l15;
        if (g == 0) { m_lds[w * 32 + t] = m_run[tf]; l_lds[w * 32 + t] = l_run[tf]; }
#pragma unroll
        for (int mf = 0; mf < 4; ++mf) {
            int su = (mf * 4 + g) ^ l15;
            *(f32x4*)&O_lds[(size_t)(w * 32 + t) * 64 + su * 4] = o[mf][tf];
        }
    }
    __syncthreads();
    {
        int t = tid >> 4, u = tid & 15;
        float mv[8];
        float M = -3e38f;
#pragma unroll
        for (int ww = 0; ww < 8; ++ww) {
            mv[ww] = m_lds[ww * 32 + t];
            M = fmaxf(M, mv[ww]);
        }
        float L = 0.f;
        f32x4 acc = {};
#pragma unroll
        for (int ww = 0; ww < 8; ++ww) {
            float wt = exp2f((mv[ww] - M) * 1.44269504f);
            L += wt * l_lds[ww * 32 + t];
            f32x4 ov = *(const f32x4*)&O_lds[(size_t)(ww * 32 + t) * 64 +
                                             ((u ^ (t & 15)) * 4)];
            acc += ov * wt;
        }
        float inv = 1.f / L;
        *(f32x4*)(out + (size_t)(base + t0 + t) * 64 + u * 4) = acc * inv;
    }
}

// ---------------------------------------------------------------------------
extern "C" void kernel_launch(void* const* d_in, const int* in_sizes, int n_in,
                              void* d_out, int out_size, void* d_ws, size_t ws_size,
                              hipStream_t stream) {
    const float* idx = (const float*)d_in[0];
    const float* Wk = (const float*)d_in[1];
    const float* Wq = (const float*)d_in[2];
    const float* Wv = (const float*)d_in[3];
    float* out = (float*)d_out;

    unsigned short* wt = (unsigned short*)d_ws;
    unsigned short* kw = wt + 192 * 1024;
    unsigned short* qw = kw + (size_t)BT_ * 64;
    unsigned short* vtw = qw + (size_t)BT_ * 64;

    wprep<<<48, 256, 0, stream>>>(Wk, Wq, Wv, wt);
    proj_gemm<<<256, 256, 0, stream>>>(idx, wt, kw, qw, vtw);
    attn<<<512, 512, 0, stream>>>(kw, qw, vtw, out);
}